// Round 5
// baseline (428.307 us; speedup 1.0000x reference)
//
#include <hip/hip_runtime.h>
#include <stdint.h>

typedef __bf16 bf16;
typedef bf16 bf16x8 __attribute__((ext_vector_type(8)));
typedef float f32x4 __attribute__((ext_vector_type(4)));

#define B_ROWS   65536
#define K1       784
#define CAPW     64         // per-wave flag-list capacity (expected ~6 flags/wave)
#define NWAVES   4096       // 1024 blocks x 4 waves

// workspace layout (bytes)
#define CNT_OFF  0          // 4096 u32 per-wave flag counts (16 KB)
#define LIST_OFF 16384      // 4096*64*4 B = 1 MB per-wave flag segments
#define S1F_OFF  1064960    // 409600 B fragment-tiled sign(w1), zero-padded K->800
#define W2P_OFF  1474560    // 128x8 u32 packed sign(w2)
#define W3P_OFF  1478656    // 32x4 u32 packed sign(w3)
#define W4P_OFF  1479168    // 16 u32 packed sign(w4)
#define H1P_OFF  1479680    // 65536x8 u32 packed h1 signs -> 2 MB

#define AS1C(p) ((const __attribute__((address_space(1))) void*)(p))
#define AS3(p)  ((__attribute__((address_space(3))) void*)(p))

// ---------------- prep: binarize/pack weights ----------------
// s1f fragment-tiled layout: element e = (((step*16 + ntile)*64 + lane)*8 + j)
//   holds sign(w1)[ntile*16 + (lane&15)][step*32 + (lane>>4)*8 + j], 0 for k>=784.
__global__ __launch_bounds__(256) void prep_kernel(
    const float* __restrict__ w1, const float* __restrict__ w2,
    const float* __restrict__ w3, const float* __restrict__ w4,
    bf16* __restrict__ s1f, uint32_t* __restrict__ w2p,
    uint32_t* __restrict__ w3p, uint32_t* __restrict__ w4p) {
  int gid = blockIdx.x * 256 + threadIdx.x;   // 0..204799 == 25*16*64*8
  {
    int j = gid & 7, l = (gid >> 3) & 63, t = (gid >> 9) & 15, s = gid >> 13;
    int fr = l & 15, fg = l >> 4;
    int n = t * 16 + fr;
    int k = s * 32 + fg * 8 + j;
    bf16 v = (bf16)0.0f;
    if (k < K1) v = (w1[n * K1 + k] >= 0.0f) ? (bf16)1.0f : (bf16)-1.0f;
    s1f[gid] = v;
  }
  if (gid < 1024) {                       // w2: 128 rows x 8 words
    int j = gid >> 3, w = gid & 7;
    uint32_t bits = 0;
    for (int i = 0; i < 32; ++i)
      bits |= (w2[j * 256 + w * 32 + i] >= 0.0f ? 1u : 0u) << i;
    w2p[gid] = bits;
  }
  if (gid < 128) {                        // w3: 32 rows x 4 words
    int j = gid >> 2, w = gid & 3;
    uint32_t bits = 0;
    for (int i = 0; i < 32; ++i)
      bits |= (w3[j * 128 + w * 32 + i] >= 0.0f ? 1u : 0u) << i;
    w3p[gid] = bits;
  }
  if (gid < 16) {                         // w4: 10 rows x 1 word (pad to 16)
    uint32_t bits = 0;
    if (gid < 10)
      for (int i = 0; i < 32; ++i)
        bits |= (w4[gid * 32 + i] >= 0.0f ? 1u : 0u) << i;
    w4p[gid] = bits;
  }
}

// ---------------- layer 1: x @ sign(w1)^T via split-bf16 MFMA ----------------
// ATOMIC-FREE (R3) + LDS-shared B (R4). R5 change: OCCUPANCY 2x.
// R4 post-mortem: unified-RF charge was 128 arch VGPR + 128 AGPR acc = 256
// regs/wave -> 2 waves/SIMD, and grid 512 = 2 blocks/CU also capped at 2.
// With one barrier/K-step, 2 waves/SIMD can't hide ~900cy HBM A-loads.
// Fix: wave tile 16x256 (acc = 64 regs), 64-row block tiles, grid 1024,
// __launch_bounds__(256,4) -> 4 waves/SIMD, 4 blocks/CU (LDS 4x32=128KB).
// Same MFMA shape/fragments/accumulation order -> v values bit-identical ->
// same flag set -> exact-cleanup path preserved (absmax=0).
__global__ __launch_bounds__(256, 4) void gemm1_kernel(
    const float* __restrict__ x, const bf16* __restrict__ s1f,
    uint8_t* __restrict__ h1b, uint32_t* __restrict__ cntArr,
    uint32_t* __restrict__ list) {
  __shared__ __align__(16) bf16 Bs[2][8192];   // 2 x 16KB B double-buffer

  const int tid = threadIdx.x;
  const int lane = tid & 63;
  const int wid = tid >> 6;
  const int fr = lane & 15, fg = lane >> 4;
  const int m0 = blockIdx.x * 64 + wid * 16;    // wave's first output row
  const int waveId = blockIdx.x * 4 + wid;

  f32x4 acc[16];
#pragma unroll
  for (int j = 0; j < 16; ++j) acc[j] = (f32x4){0.f, 0.f, 0.f, 0.f};

  // A: lane reads row (m0 + fr), k = t*32 + fg*8 .. +7  (two float4)
  const float* xp0 = x + (size_t)(m0 + fr) * K1 + fg * 8;

  float4 ar[2][2];   // [parity][half] raw fp32 A, ping-pong prefetch

  // B staging: wave wid stages frags wid*4..wid*4+3 of step t_ (1KB each).
  // Per-lane global src = base + lane*16B; HW writes LDS at dest + lane*16.
#define STAGE_B(buf_, t_)                                                      \
  {                                                                            \
    _Pragma("unroll") for (int c = 0; c < 4; ++c)                              \
        __builtin_amdgcn_global_load_lds(                                      \
            AS1C(s1f + ((size_t)(t_) * 16 + wid * 4 + c) * 512 + lane * 8),    \
            AS3(&Bs[buf_][(wid * 4 + c) * 512]), 16, 0, 0);                    \
  }

#define LOAD_A(par_, t_)                                                       \
  {                                                                            \
    ar[par_][0] = *(const float4*)(xp0 + (t_) * 32);                           \
    ar[par_][1] = *(const float4*)(xp0 + (t_) * 32 + 4);                       \
  }

  // t=24 tail: k = 768 + fg*8; only fg<2 is in-bounds (k<784); rest zero.
#define LOAD_A24(par_)                                                         \
  {                                                                            \
    float4 z = make_float4(0.f, 0.f, 0.f, 0.f);                                \
    if (fg < 2) {                                                              \
      ar[par_][0] = *(const float4*)(xp0 + 24 * 32);                           \
      ar[par_][1] = *(const float4*)(xp0 + 24 * 32 + 4);                       \
    } else {                                                                   \
      ar[par_][0] = z; ar[par_][1] = z;                                        \
    }                                                                          \
  }

  // one K-step: prefetch next A (regs) + stage next B (LDS buf cur^1) while
  // doing this step's MFMAs from LDS buf cur; ONE barrier at step end drains
  // both (vmcnt+lgkmcnt) and closes the read window on buf cur.
#define STEP(t_, cur_, nxt_, PF_)                                              \
  {                                                                            \
    if ((PF_) == 1) LOAD_A(nxt_, (t_) + 1)                                     \
    else if ((PF_) == 2) LOAD_A24(nxt_)                                        \
    if ((PF_) != 0) STAGE_B((cur_) ^ 1, (t_) + 1)                              \
    bf16x8 ah, al;                                                             \
    {                                                                          \
      float4 v0 = ar[cur_][0], v1 = ar[cur_][1];                               \
      bf16 h0 = (bf16)v0.x, h1 = (bf16)v0.y, h2 = (bf16)v0.z, h3 = (bf16)v0.w; \
      bf16 h4 = (bf16)v1.x, h5 = (bf16)v1.y, h6 = (bf16)v1.z, h7 = (bf16)v1.w; \
      bf16 l0 = (bf16)(v0.x - (float)h0), l1 = (bf16)(v0.y - (float)h1);       \
      bf16 l2 = (bf16)(v0.z - (float)h2), l3 = (bf16)(v0.w - (float)h3);       \
      bf16 l4 = (bf16)(v1.x - (float)h4), l5 = (bf16)(v1.y - (float)h5);       \
      bf16 l6 = (bf16)(v1.z - (float)h6), l7 = (bf16)(v1.w - (float)h7);       \
      ah = (bf16x8){h0, h1, h2, h3, h4, h5, h6, h7};                           \
      al = (bf16x8){l0, l1, l2, l3, l4, l5, l6, l7};                           \
    }                                                                          \
    _Pragma("unroll") for (int jg = 0; jg < 4; ++jg) {                         \
      bf16x8 b0 = *(const bf16x8*)&Bs[cur_][(jg * 4 + 0) * 512 + lane * 8];    \
      bf16x8 b1 = *(const bf16x8*)&Bs[cur_][(jg * 4 + 1) * 512 + lane * 8];    \
      bf16x8 b2 = *(const bf16x8*)&Bs[cur_][(jg * 4 + 2) * 512 + lane * 8];    \
      bf16x8 b3 = *(const bf16x8*)&Bs[cur_][(jg * 4 + 3) * 512 + lane * 8];    \
      acc[jg * 4 + 0] = __builtin_amdgcn_mfma_f32_16x16x32_bf16(ah, b0, acc[jg * 4 + 0], 0, 0, 0); \
      acc[jg * 4 + 0] = __builtin_amdgcn_mfma_f32_16x16x32_bf16(al, b0, acc[jg * 4 + 0], 0, 0, 0); \
      acc[jg * 4 + 1] = __builtin_amdgcn_mfma_f32_16x16x32_bf16(ah, b1, acc[jg * 4 + 1], 0, 0, 0); \
      acc[jg * 4 + 1] = __builtin_amdgcn_mfma_f32_16x16x32_bf16(al, b1, acc[jg * 4 + 1], 0, 0, 0); \
      acc[jg * 4 + 2] = __builtin_amdgcn_mfma_f32_16x16x32_bf16(ah, b2, acc[jg * 4 + 2], 0, 0, 0); \
      acc[jg * 4 + 2] = __builtin_amdgcn_mfma_f32_16x16x32_bf16(al, b2, acc[jg * 4 + 2], 0, 0, 0); \
      acc[jg * 4 + 3] = __builtin_amdgcn_mfma_f32_16x16x32_bf16(ah, b3, acc[jg * 4 + 3], 0, 0, 0); \
      acc[jg * 4 + 3] = __builtin_amdgcn_mfma_f32_16x16x32_bf16(al, b3, acc[jg * 4 + 3], 0, 0, 0); \
    }                                                                          \
    if ((PF_) != 0) __syncthreads();                                           \
  }

  STAGE_B(0, 0)
  LOAD_A(0, 0)
  __syncthreads();   // drains stage(0) (vmcnt0) before first LDS reads

  for (int tt = 0; tt < 11; ++tt) {       // steps 0..21
    STEP(2 * tt,     0, 1, 1)
    STEP(2 * tt + 1, 1, 0, 1)
  }
  STEP(22, 0, 1, 1)                       // prefetch A(23), stage B(23)
  STEP(23, 1, 0, 2)                       // guarded prefetch A(24), stage B(24)
  STEP(24, 0, 0, 0)                       // tail, no prefetch, no barrier

  // epilogue: pack signs via ballot; flag |v|<0.05 into the wave's PRIVATE
  // list segment (wave-uniform register count, zero atomics).
  // C/D layout: col = j*16 + (lane&15), row = m0 + (lane>>4)*4 + reg.
  uint32_t* wlist = list + (size_t)waveId * CAPW;
  uint32_t wcnt = 0;

#define FLAG(v_, jj_, rr_)                                                     \
  {                                                                            \
    unsigned long long fb = __ballot(__builtin_fabsf(v_) < 0.05f);             \
    if (fb) {                                                                  \
      if (__builtin_fabsf(v_) < 0.05f) {                                       \
        uint32_t pos = wcnt + (uint32_t)__popcll(fb & ((1ull << lane) - 1ull));\
        if (pos < CAPW)                                                        \
          wlist[pos] = ((uint32_t)(m0 + fg * 4 + (rr_)) << 8) |                \
                       (uint32_t)((jj_) * 16 + fr);                            \
      }                                                                        \
      wcnt += (uint32_t)__popcll(fb);                                          \
    }                                                                          \
  }

#pragma unroll
  for (int r = 0; r < 4; ++r) {
    uint32_t w[8];
#pragma unroll
    for (int jp = 0; jp < 8; ++jp) {
      float v0 = acc[2 * jp][r];
      float v1 = acc[2 * jp + 1][r];
      unsigned long long s0 = __ballot(v0 >= 0.0f);
      unsigned long long s1 = __ballot(v1 >= 0.0f);
      FLAG(v0, 2 * jp, r)
      FLAG(v1, 2 * jp + 1, r)
      w[jp] = (uint32_t)((s0 >> (fg * 16)) & 0xFFFF) |
              ((uint32_t)((s1 >> (fg * 16)) & 0xFFFF) << 16);
    }
    if (fr == 0) {   // lanes 0,16,32,48: each writes its own row's 256 bits
      int m = m0 + fg * 4 + r;
      *(uint4*)(h1b + (size_t)m * 32)      = make_uint4(w[0], w[1], w[2], w[3]);
      *(uint4*)(h1b + (size_t)m * 32 + 16) = make_uint4(w[4], w[5], w[6], w[7]);
    }
  }

  if (lane == 0) cntArr[waveId] = (wcnt < CAPW) ? wcnt : CAPW;
}

// ---------------- cleanup: recompute flagged dots EXACTLY as the fp32 reference ----------------
// VERIFIED (absmax=0): reference = BLIS/AOCL-style sgemm, KC=512, full panels
// then remainder; one fp32 accumulator per C element, ascending k in panel;
// C = fl( seq[0,512) + seq[512,784) ).
// Iterates per-wave list segments: slot idx -> wave idx>>6, local idx&63.
__global__ __launch_bounds__(256) void cleanup_kernel(
    const float* __restrict__ x, const float* __restrict__ w1,
    uint32_t* __restrict__ h1p, const uint32_t* __restrict__ cntArr,
    const uint32_t* __restrict__ list) {
  for (uint32_t idx = blockIdx.x * 256 + threadIdx.x; idx < NWAVES * CAPW;
       idx += 65536) {
    uint32_t w = idx >> 6, li = idx & (CAPW - 1);
    if (li >= cntArr[w]) continue;
    uint32_t e = list[idx];
    uint32_t col = e & 255u, b = e >> 8;
    const float4* xr4 = (const float4*)(x + (size_t)b * K1);
    const float4* wr4 = (const float4*)(w1 + (size_t)col * K1);
    float t1 = 0.0f, t2 = 0.0f;
    for (int k4 = 0; k4 < 128; ++k4) {          // k in [0,512)
      float4 xv = xr4[k4], wv = wr4[k4];
      t1 += (wv.x >= 0.f) ? xv.x : -xv.x;
      t1 += (wv.y >= 0.f) ? xv.y : -xv.y;
      t1 += (wv.z >= 0.f) ? xv.z : -xv.z;
      t1 += (wv.w >= 0.f) ? xv.w : -xv.w;
    }
    for (int k4 = 128; k4 < 196; ++k4) {        // k in [512,784)
      float4 xv = xr4[k4], wv = wr4[k4];
      t2 += (wv.x >= 0.f) ? xv.x : -xv.x;
      t2 += (wv.y >= 0.f) ? xv.y : -xv.y;
      t2 += (wv.z >= 0.f) ? xv.z : -xv.z;
      t2 += (wv.w >= 0.f) ? xv.w : -xv.w;
    }
    float s = t1 + t2;   // single K-panel join at 512 (BLIS KC)
    uint32_t word = b * 8u + (col >> 5);
    uint32_t mask = 1u << (col & 31u);
    if (s >= 0.0f) atomicOr(&h1p[word], mask);
    else           atomicAnd(&h1p[word], ~mask);
  }
}

// ---------------- layers 2-4: xor/popcount, one thread per batch row ----------------
__global__ __launch_bounds__(256) void layer234_kernel(
    const uint32_t* __restrict__ h1p, const uint32_t* __restrict__ w2p,
    const uint32_t* __restrict__ w3p, const uint32_t* __restrict__ w4p,
    float* __restrict__ out) {
  __shared__ __align__(16) uint32_t lw[1168];  // [0,1024) w2p, [1024,1152) w3p, [1152,1168) w4p
  for (int i = threadIdx.x; i < 1168; i += 256) {
    uint32_t v;
    if (i < 1024) v = w2p[i];
    else if (i < 1152) v = w3p[i - 1024];
    else v = w4p[i - 1152];
    lw[i] = v;
  }
  __syncthreads();
  int b = blockIdx.x * 256 + threadIdx.x;
  const uint4* hp = (const uint4*)h1p;
  uint4 a0 = hp[(size_t)b * 2], a1 = hp[(size_t)b * 2 + 1];

  uint32_t h2w[4] = {0u, 0u, 0u, 0u};
#pragma unroll 4
  for (int j = 0; j < 128; ++j) {
    uint4 w0 = *(const uint4*)&lw[j * 8];
    uint4 w1v = *(const uint4*)&lw[j * 8 + 4];
    int t = __popc(a0.x ^ w0.x) + __popc(a0.y ^ w0.y) +
            __popc(a0.z ^ w0.z) + __popc(a0.w ^ w0.w) +
            __popc(a1.x ^ w1v.x) + __popc(a1.y ^ w1v.y) +
            __popc(a1.z ^ w1v.z) + __popc(a1.w ^ w1v.w);
    h2w[j >> 5] |= (uint32_t)(t <= 128) << (j & 31);   // dot = 256-2t >= 0
  }
  uint32_t h3 = 0u;
#pragma unroll 4
  for (int j = 0; j < 32; ++j) {
    uint4 w0 = *(const uint4*)&lw[1024 + j * 4];
    int t = __popc(h2w[0] ^ w0.x) + __popc(h2w[1] ^ w0.y) +
            __popc(h2w[2] ^ w0.z) + __popc(h2w[3] ^ w0.w);
    h3 |= (uint32_t)(t <= 64) << j;                    // dot = 128-2t >= 0
  }
  float* o = out + (size_t)b * 10;
#pragma unroll
  for (int c = 0; c < 10; ++c) {
    int t = __popc(h3 ^ lw[1152 + c]);
    o[c] = (float)(32 - 2 * t);                        // final logits, no step
  }
}

extern "C" void kernel_launch(void* const* d_in, const int* in_sizes, int n_in,
                              void* d_out, int out_size, void* d_ws, size_t ws_size,
                              hipStream_t stream) {
  const float* x  = (const float*)d_in[0];
  const float* w1 = (const float*)d_in[1];
  const float* w2 = (const float*)d_in[2];
  const float* w3 = (const float*)d_in[3];
  const float* w4 = (const float*)d_in[4];
  float* out = (float*)d_out;
  uint8_t* ws = (uint8_t*)d_ws;

  uint32_t* cntArr = (uint32_t*)(ws + CNT_OFF);
  uint32_t* list   = (uint32_t*)(ws + LIST_OFF);
  bf16*     s1f    = (bf16*)(ws + S1F_OFF);
  uint32_t* w2p    = (uint32_t*)(ws + W2P_OFF);
  uint32_t* w3p    = (uint32_t*)(ws + W3P_OFF);
  uint32_t* w4p    = (uint32_t*)(ws + W4P_OFF);
  uint32_t* h1p    = (uint32_t*)(ws + H1P_OFF);

  prep_kernel<<<800, 256, 0, stream>>>(w1, w2, w3, w4, s1f, w2p, w3p, w4p);
  gemm1_kernel<<<1024, 256, 0, stream>>>(x, s1f, (uint8_t*)h1p, cntArr, list);
  cleanup_kernel<<<256, 256, 0, stream>>>(x, w1, h1p, cntArr, list);
  layer234_kernel<<<B_ROWS / 256, 256, 0, stream>>>(h1p, w2p, w3p, w4p, out);
}

// Round 6
// 375.407 us; speedup vs baseline: 1.1409x; 1.1409x over previous
//
#include <hip/hip_runtime.h>
#include <stdint.h>

typedef __bf16 bf16;
typedef bf16 bf16x8 __attribute__((ext_vector_type(8)));
typedef float f32x4 __attribute__((ext_vector_type(4)));

#define B_ROWS   65536
#define K1       784

// workspace layout (bytes) -- only prep outputs now; flag/h1 intermediates are gone
#define S1F_OFF  0          // 409600 B fragment-tiled sign(w1), zero-padded K->800
#define W2P_OFF  409600     // 128x8 u32 packed sign(w2)
#define W3P_OFF  413696     // 32x4 u32 packed sign(w3)
#define W4P_OFF  414208     // 16 u32 packed sign(w4)

#define AS1C(p) ((const __attribute__((address_space(1))) void*)(p))
#define AS3(p)  ((__attribute__((address_space(3))) void*)(p))

// ---------------- prep: binarize/pack weights ----------------
// s1f fragment-tiled layout: element e = (((step*16 + ntile)*64 + lane)*8 + j)
//   holds sign(w1)[ntile*16 + (lane&15)][step*32 + (lane>>4)*8 + j], 0 for k>=784.
__global__ __launch_bounds__(256) void prep_kernel(
    const float* __restrict__ w1, const float* __restrict__ w2,
    const float* __restrict__ w3, const float* __restrict__ w4,
    bf16* __restrict__ s1f, uint32_t* __restrict__ w2p,
    uint32_t* __restrict__ w3p, uint32_t* __restrict__ w4p) {
  int gid = blockIdx.x * 256 + threadIdx.x;   // 0..204799 == 25*16*64*8
  {
    int j = gid & 7, l = (gid >> 3) & 63, t = (gid >> 9) & 15, s = gid >> 13;
    int fr = l & 15, fg = l >> 4;
    int n = t * 16 + fr;
    int k = s * 32 + fg * 8 + j;
    bf16 v = (bf16)0.0f;
    if (k < K1) v = (w1[n * K1 + k] >= 0.0f) ? (bf16)1.0f : (bf16)-1.0f;
    s1f[gid] = v;
  }
  if (gid < 1024) {                       // w2: 128 rows x 8 words
    int j = gid >> 3, w = gid & 7;
    uint32_t bits = 0;
    for (int i = 0; i < 32; ++i)
      bits |= (w2[j * 256 + w * 32 + i] >= 0.0f ? 1u : 0u) << i;
    w2p[gid] = bits;
  }
  if (gid < 128) {                        // w3: 32 rows x 4 words
    int j = gid >> 2, w = gid & 3;
    uint32_t bits = 0;
    for (int i = 0; i < 32; ++i)
      bits |= (w3[j * 128 + w * 32 + i] >= 0.0f ? 1u : 0u) << i;
    w3p[gid] = bits;
  }
  if (gid < 16) {                         // w4: 10 rows x 1 word (pad to 16)
    uint32_t bits = 0;
    if (gid < 10)
      for (int i = 0; i < 32; ++i)
        bits |= (w4[gid * 32 + i] >= 0.0f ? 1u : 0u) << i;
    w4p[gid] = bits;
  }
}

// ---------------- fused forward: gemm1 + exact-fix + layers 2-4 ----------------
// R5 post-mortem: occupancy 2x did NOT move gemm1 (2 failed latency theories);
// the big controllable budget is the dispatch chain itself (~165us of cleanup+
// layer234+launch gaps beyond the fixed 120us workspace re-poison). Structural
// fact: each wave computes the FULL 256-wide h1 row for its 16 rows -> layers
// 2-4 and the flag corrections are wave-local. This kernel fuses everything:
//   - K-loop: byte-identical to R5 (LDS-shared B via global_load_lds, 1
//     barrier/step, atomic-free).
//   - epilogue: ballots -> h1 bits in registers; flags -> per-wave LDS list;
//     parallel exact-recompute pass (verbatim BLIS-order fp32 loop, bit-exact)
//     patches bits via wave-private LDS atomics; then 16 lanes/wave run the
//     xor/popcount layers 2-4 and write logits directly.
// h1p/list/cnt globals and the cleanup/layer234 dispatches are deleted.
__global__ __launch_bounds__(256, 4) void fused_kernel(
    const float* __restrict__ x, const bf16* __restrict__ s1f,
    const float* __restrict__ w1, const uint32_t* __restrict__ w2p,
    const uint32_t* __restrict__ w3p, const uint32_t* __restrict__ w4p,
    float* __restrict__ out) {
  __shared__ __align__(16) bf16 Bs[2][8192];     // 2 x 16KB B double-buffer
  __shared__ __align__(16) uint32_t lw[1168];    // packed w2|w3|w4 words
  __shared__ __align__(16) uint32_t h1w[4][16][8]; // per-wave h1 row bits
  __shared__ uint32_t flg[4][48];                // per-wave flag lists

  const int tid = threadIdx.x;
  const int lane = tid & 63;
  const int wid = tid >> 6;
  const int fr = lane & 15, fg = lane >> 4;
  const int m0 = blockIdx.x * 64 + wid * 16;     // wave's first output row

  f32x4 acc[16];
#pragma unroll
  for (int j = 0; j < 16; ++j) acc[j] = (f32x4){0.f, 0.f, 0.f, 0.f};

  // A: lane reads row (m0 + fr), k = t*32 + fg*8 .. +7  (two float4)
  const float* xp0 = x + (size_t)(m0 + fr) * K1 + fg * 8;

  float4 ar[2][2];   // [parity][half] raw fp32 A, ping-pong prefetch

  // B staging: wave wid stages frags wid*4..wid*4+3 of step t_ (1KB each).
#define STAGE_B(buf_, t_)                                                      \
  {                                                                            \
    _Pragma("unroll") for (int c = 0; c < 4; ++c)                              \
        __builtin_amdgcn_global_load_lds(                                      \
            AS1C(s1f + ((size_t)(t_) * 16 + wid * 4 + c) * 512 + lane * 8),    \
            AS3(&Bs[buf_][(wid * 4 + c) * 512]), 16, 0, 0);                    \
  }

#define LOAD_A(par_, t_)                                                       \
  {                                                                            \
    ar[par_][0] = *(const float4*)(xp0 + (t_) * 32);                           \
    ar[par_][1] = *(const float4*)(xp0 + (t_) * 32 + 4);                       \
  }

  // t=24 tail: k = 768 + fg*8; only fg<2 is in-bounds (k<784); rest zero.
#define LOAD_A24(par_)                                                         \
  {                                                                            \
    float4 z = make_float4(0.f, 0.f, 0.f, 0.f);                                \
    if (fg < 2) {                                                              \
      ar[par_][0] = *(const float4*)(xp0 + 24 * 32);                           \
      ar[par_][1] = *(const float4*)(xp0 + 24 * 32 + 4);                       \
    } else {                                                                   \
      ar[par_][0] = z; ar[par_][1] = z;                                        \
    }                                                                          \
  }

#define STEP(t_, cur_, nxt_, PF_)                                              \
  {                                                                            \
    if ((PF_) == 1) LOAD_A(nxt_, (t_) + 1)                                     \
    else if ((PF_) == 2) LOAD_A24(nxt_)                                        \
    if ((PF_) != 0) STAGE_B((cur_) ^ 1, (t_) + 1)                              \
    bf16x8 ah, al;                                                             \
    {                                                                          \
      float4 v0 = ar[cur_][0], v1 = ar[cur_][1];                               \
      bf16 h0 = (bf16)v0.x, h1 = (bf16)v0.y, h2 = (bf16)v0.z, h3 = (bf16)v0.w; \
      bf16 h4 = (bf16)v1.x, h5 = (bf16)v1.y, h6 = (bf16)v1.z, h7 = (bf16)v1.w; \
      bf16 l0 = (bf16)(v0.x - (float)h0), l1 = (bf16)(v0.y - (float)h1);       \
      bf16 l2 = (bf16)(v0.z - (float)h2), l3 = (bf16)(v0.w - (float)h3);       \
      bf16 l4 = (bf16)(v1.x - (float)h4), l5 = (bf16)(v1.y - (float)h5);       \
      bf16 l6 = (bf16)(v1.z - (float)h6), l7 = (bf16)(v1.w - (float)h7);       \
      ah = (bf16x8){h0, h1, h2, h3, h4, h5, h6, h7};                           \
      al = (bf16x8){l0, l1, l2, l3, l4, l5, l6, l7};                           \
    }                                                                          \
    _Pragma("unroll") for (int jg = 0; jg < 4; ++jg) {                         \
      bf16x8 b0 = *(const bf16x8*)&Bs[cur_][(jg * 4 + 0) * 512 + lane * 8];    \
      bf16x8 b1 = *(const bf16x8*)&Bs[cur_][(jg * 4 + 1) * 512 + lane * 8];    \
      bf16x8 b2 = *(const bf16x8*)&Bs[cur_][(jg * 4 + 2) * 512 + lane * 8];    \
      bf16x8 b3 = *(const bf16x8*)&Bs[cur_][(jg * 4 + 3) * 512 + lane * 8];    \
      acc[jg * 4 + 0] = __builtin_amdgcn_mfma_f32_16x16x32_bf16(ah, b0, acc[jg * 4 + 0], 0, 0, 0); \
      acc[jg * 4 + 0] = __builtin_amdgcn_mfma_f32_16x16x32_bf16(al, b0, acc[jg * 4 + 0], 0, 0, 0); \
      acc[jg * 4 + 1] = __builtin_amdgcn_mfma_f32_16x16x32_bf16(ah, b1, acc[jg * 4 + 1], 0, 0, 0); \
      acc[jg * 4 + 1] = __builtin_amdgcn_mfma_f32_16x16x32_bf16(al, b1, acc[jg * 4 + 1], 0, 0, 0); \
      acc[jg * 4 + 2] = __builtin_amdgcn_mfma_f32_16x16x32_bf16(ah, b2, acc[jg * 4 + 2], 0, 0, 0); \
      acc[jg * 4 + 2] = __builtin_amdgcn_mfma_f32_16x16x32_bf16(al, b2, acc[jg * 4 + 2], 0, 0, 0); \
      acc[jg * 4 + 3] = __builtin_amdgcn_mfma_f32_16x16x32_bf16(ah, b3, acc[jg * 4 + 3], 0, 0, 0); \
      acc[jg * 4 + 3] = __builtin_amdgcn_mfma_f32_16x16x32_bf16(al, b3, acc[jg * 4 + 3], 0, 0, 0); \
    }                                                                          \
    if ((PF_) != 0) __syncthreads();                                           \
  }

  // cooperative lw load rides under the first barrier
  for (int i = tid; i < 1168; i += 256) {
    uint32_t v;
    if (i < 1024) v = w2p[i];
    else if (i < 1152) v = w3p[i - 1024];
    else v = w4p[i - 1152];
    lw[i] = v;
  }
  STAGE_B(0, 0)
  LOAD_A(0, 0)
  __syncthreads();   // drains stage(0) + lw writes before first reads

  for (int tt = 0; tt < 11; ++tt) {       // steps 0..21
    STEP(2 * tt,     0, 1, 1)
    STEP(2 * tt + 1, 1, 0, 1)
  }
  STEP(22, 0, 1, 1)                       // prefetch A(23), stage B(23)
  STEP(23, 1, 0, 2)                       // guarded prefetch A(24), stage B(24)
  STEP(24, 0, 0, 0)                       // tail, no prefetch, no barrier

  // ---------------- fused epilogue ----------------
  // C/D layout: col = j*16 + (lane&15), row = m0 + (lane>>4)*4 + reg.
  // Ballots are wave-uniform, so EVERY lane can assemble any row's bits:
  // lane i (i = lane&15) collects the 8 words of row m0+i.
  uint32_t* wflg = &flg[wid][0];
  uint32_t* wh1  = &h1w[wid][0][0];
  uint32_t wcnt = 0;
  const int myrow = lane & 15;

#define FLAG(v_, jj_, rr_)                                                     \
  {                                                                            \
    unsigned long long fb = __ballot(__builtin_fabsf(v_) < 0.05f);             \
    if (fb) {                                                                  \
      if (__builtin_fabsf(v_) < 0.05f) {                                       \
        uint32_t pos = wcnt + (uint32_t)__popcll(fb & ((1ull << lane) - 1ull));\
        if (pos < 48)                                                          \
          wflg[pos] = ((uint32_t)(fg * 4 + (rr_)) << 8) |                      \
                      (uint32_t)((jj_) * 16 + fr);                             \
      }                                                                        \
      wcnt += (uint32_t)__popcll(fb);                                          \
    }                                                                          \
  }

  uint32_t myw[8] = {0u, 0u, 0u, 0u, 0u, 0u, 0u, 0u};
#pragma unroll
  for (int r = 0; r < 4; ++r) {
#pragma unroll
    for (int jp = 0; jp < 8; ++jp) {
      float v0 = acc[2 * jp][r];
      float v1 = acc[2 * jp + 1][r];
      unsigned long long s0 = __ballot(v0 >= 0.0f);
      unsigned long long s1 = __ballot(v1 >= 0.0f);
      FLAG(v0, 2 * jp, r)
      FLAG(v1, 2 * jp + 1, r)
      uint32_t wv = (uint32_t)((s0 >> ((myrow >> 2) * 16)) & 0xFFFF) |
                    ((uint32_t)((s1 >> ((myrow >> 2) * 16)) & 0xFFFF) << 16);
      if ((myrow & 3) == r) myw[jp] = wv;
    }
  }
  if (lane < 16) {   // stage uncorrected bits: row myrow, 8 words
    *(uint4*)&wh1[myrow * 8]     = make_uint4(myw[0], myw[1], myw[2], myw[3]);
    *(uint4*)&wh1[myrow * 8 + 4] = make_uint4(myw[4], myw[5], myw[6], myw[7]);
  }
  asm volatile("s_waitcnt lgkmcnt(0)" ::: "memory");

  // parallel exact-fix: lane e recomputes flag entry e with the VERIFIED
  // (absmax=0) BLIS-order fp32 loop: KC=512 panel + remainder, ascending k,
  // one accumulator per panel, single join at 512. Bit-exact vs reference.
  uint32_t nf = (wcnt < 48) ? wcnt : 48;
  if (lane < nf) {
    uint32_t e = wflg[lane];
    uint32_t col = e & 255u, mlocal = e >> 8;
    const float4* xr4 = (const float4*)(x + (size_t)(m0 + mlocal) * K1);
    const float4* wr4 = (const float4*)(w1 + (size_t)col * K1);
    float t1 = 0.0f, t2 = 0.0f;
    for (int k4 = 0; k4 < 128; ++k4) {          // k in [0,512)
      float4 xv = xr4[k4], wv = wr4[k4];
      t1 += (wv.x >= 0.f) ? xv.x : -xv.x;
      t1 += (wv.y >= 0.f) ? xv.y : -xv.y;
      t1 += (wv.z >= 0.f) ? xv.z : -xv.z;
      t1 += (wv.w >= 0.f) ? xv.w : -xv.w;
    }
    for (int k4 = 128; k4 < 196; ++k4) {        // k in [512,784)
      float4 xv = xr4[k4], wv = wr4[k4];
      t2 += (wv.x >= 0.f) ? xv.x : -xv.x;
      t2 += (wv.y >= 0.f) ? xv.y : -xv.y;
      t2 += (wv.z >= 0.f) ? xv.z : -xv.z;
      t2 += (wv.w >= 0.f) ? xv.w : -xv.w;
    }
    float s = t1 + t2;
    uint32_t word = mlocal * 8u + (col >> 5);
    uint32_t mask = 1u << (col & 31u);
    if (s >= 0.0f) atomicOr((unsigned int*)&wh1[word], mask);
    else           atomicAnd((unsigned int*)&wh1[word], ~mask);
  }
  asm volatile("s_waitcnt vmcnt(0) lgkmcnt(0)" ::: "memory");

  // layers 2-4 for this wave's 16 rows (wave-private; no cross-wave sync)
  if (lane < 16) {
    uint4 a0 = *(const uint4*)&wh1[myrow * 8];
    uint4 a1 = *(const uint4*)&wh1[myrow * 8 + 4];
    uint32_t h2w[4] = {0u, 0u, 0u, 0u};
#pragma unroll 4
    for (int j = 0; j < 128; ++j) {
      uint4 w0 = *(const uint4*)&lw[j * 8];
      uint4 w1v = *(const uint4*)&lw[j * 8 + 4];
      int t = __popc(a0.x ^ w0.x) + __popc(a0.y ^ w0.y) +
              __popc(a0.z ^ w0.z) + __popc(a0.w ^ w0.w) +
              __popc(a1.x ^ w1v.x) + __popc(a1.y ^ w1v.y) +
              __popc(a1.z ^ w1v.z) + __popc(a1.w ^ w1v.w);
      h2w[j >> 5] |= (uint32_t)(t <= 128) << (j & 31);   // dot = 256-2t >= 0
    }
    uint32_t h3 = 0u;
#pragma unroll 4
    for (int j = 0; j < 32; ++j) {
      uint4 w0 = *(const uint4*)&lw[1024 + j * 4];
      int t = __popc(h2w[0] ^ w0.x) + __popc(h2w[1] ^ w0.y) +
              __popc(h2w[2] ^ w0.z) + __popc(h2w[3] ^ w0.w);
      h3 |= (uint32_t)(t <= 64) << j;                    // dot = 128-2t >= 0
    }
    float* o = out + (size_t)(m0 + myrow) * 10;
#pragma unroll
    for (int c = 0; c < 10; ++c) {
      int t = __popc(h3 ^ lw[1152 + c]);
      o[c] = (float)(32 - 2 * t);                        // final logits
    }
  }
}

extern "C" void kernel_launch(void* const* d_in, const int* in_sizes, int n_in,
                              void* d_out, int out_size, void* d_ws, size_t ws_size,
                              hipStream_t stream) {
  const float* x  = (const float*)d_in[0];
  const float* w1 = (const float*)d_in[1];
  const float* w2 = (const float*)d_in[2];
  const float* w3 = (const float*)d_in[3];
  const float* w4 = (const float*)d_in[4];
  float* out = (float*)d_out;
  uint8_t* ws = (uint8_t*)d_ws;

  bf16*     s1f = (bf16*)(ws + S1F_OFF);
  uint32_t* w2p = (uint32_t*)(ws + W2P_OFF);
  uint32_t* w3p = (uint32_t*)(ws + W3P_OFF);
  uint32_t* w4p = (uint32_t*)(ws + W4P_OFF);

  prep_kernel<<<800, 256, 0, stream>>>(w1, w2, w3, w4, s1f, w2p, w3p, w4p);
  fused_kernel<<<1024, 256, 0, stream>>>(x, s1f, w1, w2p, w3p, w4p, out);
}